// Round 6
// baseline (135486.340 us; speedup 1.0000x reference)
//
#include <hip/hip_runtime.h>

#define T_STEPS  8192
#define INPUT_N  256
#define OUTPUT_N 256
#define RES_N    4096
#define NB       256   // blocks (1 per CU)
#define NT       1024  // threads per block (16 waves)
#define RPB      16    // W_res rows per block

// Pin a value into a VGPR: the asm result is not rematerializable, so the
// backend can neither sink the feeding load into the loop nor re-load it
// from global. Requires an adequate VGPR budget (amdgpu_waves_per_eu).
#define PIN(x)  asm volatile("" : "+v"(x))
#define PIN4(v) do { PIN((v).x); PIN((v).y); PIN((v).z); PIN((v).w); } while (0)

// Persistent ESN kernel, register-resident W_res.
//
// KEY FIX vs rounds 3-5: __launch_bounds__'s 2nd arg is only a MINIMUM
// waves/EU — the backend still targeted 8 waves/EU (2 blocks/CU) and capped
// VGPRs at 64, spilling all 72 weight floats to scratch (re-read every step
// from L2/L3 = the 11 us/step). amdgpu_waves_per_eu(4,4) pins the occupancy
// target to exactly 4 waves/EU (= our grid's 1 block/CU) -> 128-VGPR budget.
//
// Decomposition: rg=tid>>8 owns rows rg*4..rg*4+3 of the block's 16 rows;
// cg=tid&255 covers state columns 4*(cg+256c), c=0..3. 64 W_res floats,
// 4 W_in floats, 4 W_out floats per thread, all pinned.
//
// Step loop (2 barriers): pollers (tid<256) spin on their block's flag,
// then immediately load that block's 16-float slice (agent-scope, parity-
// double-buffered lds_s) -> syncA -> all waves compute row partials +
// reduce4 -> syncC -> wave 0 combines+tanh+publishes slice+flag (wave-local
// threadfence, no block sync) while other waves do the W_out partial for
// the PREVIOUS state (off critical path, reduced one iteration later by
// wave 8 from parity-buffered lds_pp).
__global__ __launch_bounds__(NT)
__attribute__((amdgpu_waves_per_eu(4, 4)))
void esn_persistent(
    const float* __restrict__ X,       // [T, 256]
    const float* __restrict__ state0,  // [4096]
    const float* __restrict__ W_in,    // [4096, 256]
    const float* __restrict__ W_res,   // [4096, 4096]
    const float* __restrict__ W_out,   // [256, 4096]
    float* __restrict__ out,           // [T, 256]
    float* __restrict__ stbuf,         // ws: [2][4096]
    int*   __restrict__ flags)         // ws: [2][256], zeroed per call
{
    const int tid  = threadIdx.x;
    const int bid  = blockIdx.x;
    const int wid  = tid >> 6;          // wave 0..15
    const int lane = tid & 63;
    const int rg   = tid >> 8;          // row-group 0..3
    const int wg   = (tid >> 6) & 3;    // wave within row-group
    const int cg   = tid & 255;         // column group

    __shared__ float lds_s[2][RES_N];       // parity-buffered staged state
    __shared__ float lds_x[INPUT_N];        // staged x_t
    __shared__ float lds_part[4][4][4];     // [rg][wg][r] row partials
    __shared__ float lds_pp[2][16];         // parity-buffered pred partials

    // ---- one-time: persistent weights into registers (72 floats) ----
    float4 wres[4][4];
    float  win[4];
#pragma unroll
    for (int r = 0; r < 4; ++r) {
        const int grow = bid * RPB + rg * 4 + r;
        const float* wr = W_res + (size_t)grow * RES_N;
#pragma unroll
        for (int c = 0; c < 4; ++c)
            wres[r][c] = *(const float4*)(wr + 4 * (cg + 256 * c));
        win[r] = W_in[(size_t)grow * INPUT_N + cg];
    }
    float4 wout4 = *(const float4*)(W_out + (size_t)bid * RES_N + 4 * tid);
#pragma unroll
    for (int r = 0; r < 4; ++r) {
#pragma unroll
        for (int c = 0; c < 4; ++c) PIN4(wres[r][c]);
        PIN(win[r]);
    }
    PIN4(wout4);

#pragma unroll 1
    for (int t = 0; t <= T_STEPS; ++t) {
        const int par  = t & 1;
        const int ppar = (t + 1) & 1;

        // ---- pollers: wait for producer block's flag, then stage its slice ----
        if (t == 0) {
            if (tid < NB) {
#pragma unroll
                for (int j = 0; j < 4; ++j)
                    *(float4*)(&lds_s[1][tid * 16 + 4 * j]) =
                        *(const float4*)(state0 + tid * 16 + 4 * j);
            }
        } else if (tid < NB) {
            const int* f = flags + ppar * NB + tid;
            while (__hip_atomic_load(f, __ATOMIC_RELAXED,
                                     __HIP_MEMORY_SCOPE_AGENT) < t) { }
            // acquire: order the slice loads after the flag observation
            (void)__hip_atomic_load(f, __ATOMIC_ACQUIRE, __HIP_MEMORY_SCOPE_AGENT);
            const unsigned long long* sp =
                (const unsigned long long*)(stbuf + (size_t)ppar * RES_N + tid * 16);
            unsigned long long q[8];
#pragma unroll
            for (int j = 0; j < 8; ++j)
                q[j] = __hip_atomic_load(sp + j, __ATOMIC_RELAXED,
                                         __HIP_MEMORY_SCOPE_AGENT);
#pragma unroll
            for (int j = 0; j < 8; ++j) {
                lds_s[ppar][tid * 16 + 2 * j]     =
                    __uint_as_float((unsigned)(q[j] & 0xffffffffull));
                lds_s[ppar][tid * 16 + 2 * j + 1] =
                    __uint_as_float((unsigned)(q[j] >> 32));
            }
        }
        if (t < T_STEPS && tid >= 256 && tid < 512)
            lds_x[tid - 256] = X[(size_t)t * INPUT_N + (tid - 256)];
        __syncthreads();  // A: staged state/x visible to all waves

        // ---- row partials: 4 rows x 4 float4 chunks per thread ----
        if (t < T_STEPS) {
            float p0 = 0.f, p1 = 0.f, p2 = 0.f, p3 = 0.f;
#pragma unroll
            for (int c = 0; c < 4; ++c) {
                const float4 s = *(const float4*)(&lds_s[ppar][4 * (cg + 256 * c)]);
                p0 += wres[0][c].x * s.x + wres[0][c].y * s.y
                    + wres[0][c].z * s.z + wres[0][c].w * s.w;
                p1 += wres[1][c].x * s.x + wres[1][c].y * s.y
                    + wres[1][c].z * s.z + wres[1][c].w * s.w;
                p2 += wres[2][c].x * s.x + wres[2][c].y * s.y
                    + wres[2][c].z * s.z + wres[2][c].w * s.w;
                p3 += wres[3][c].x * s.x + wres[3][c].y * s.y
                    + wres[3][c].z * s.z + wres[3][c].w * s.w;
            }
            const float xv = lds_x[cg];
            p0 += win[0] * xv;
            p1 += win[1] * xv;
            p2 += win[2] * xv;
            p3 += win[3] * xv;
            // merged reduce4: 2 butterfly levels on all four, select, 4 more
            p0 += __shfl_xor(p0, 1, 64); p1 += __shfl_xor(p1, 1, 64);
            p2 += __shfl_xor(p2, 1, 64); p3 += __shfl_xor(p3, 1, 64);
            p0 += __shfl_xor(p0, 2, 64); p1 += __shfl_xor(p1, 2, 64);
            p2 += __shfl_xor(p2, 2, 64); p3 += __shfl_xor(p3, 2, 64);
            float v = (lane & 1) ? ((lane & 2) ? p3 : p1)
                                 : ((lane & 2) ? p2 : p0);
            v += __shfl_xor(v, 4, 64);
            v += __shfl_xor(v, 8, 64);
            v += __shfl_xor(v, 16, 64);
            v += __shfl_xor(v, 32, 64);
            if (lane < 4) lds_part[rg][wg][lane] = v;  // lane r holds row r sum
        }
        __syncthreads();  // C: partials visible

        // ---- wave 0: combine + tanh + publish slice + flag (early) ----
        if (t < T_STEPS && wid == 0) {
            if (lane < RPB) {
                const int lrg = lane >> 2, lr = lane & 3;
                const float s = lds_part[lrg][0][lr] + lds_part[lrg][1][lr]
                              + lds_part[lrg][2][lr] + lds_part[lrg][3][lr];
                const float ns = tanhf(s);
                __hip_atomic_store(stbuf + (size_t)par * RES_N + bid * RPB + lane,
                                   ns, __ATOMIC_RELAXED, __HIP_MEMORY_SCOPE_AGENT);
            }
            __threadfence();  // wave-local: drains wave 0's 16 stores to L3
            if (lane == 0)
                __hip_atomic_store(flags + par * NB + bid, t + 1,
                                   __ATOMIC_RELAXED, __HIP_MEMORY_SCOPE_AGENT);
        }

        // ---- wave 8: deferred pred reduce for out[t-2] ----
        if (t >= 2 && wid == 8 && lane < 16) {
            float pv = lds_pp[ppar][lane];
            pv += __shfl_xor(pv, 8, 64);
            pv += __shfl_xor(pv, 4, 64);
            pv += __shfl_xor(pv, 2, 64);
            pv += __shfl_xor(pv, 1, 64);
            if (lane == 0) out[(size_t)(t - 2) * OUTPUT_N + bid] = pv;
        }

        // ---- all waves: pred partial for state_{t-1} (off critical path) ----
        if (t > 0) {
            const float4 s4 = *(const float4*)(&lds_s[ppar][4 * tid]);
            float pp = wout4.x * s4.x + wout4.y * s4.y
                     + wout4.z * s4.z + wout4.w * s4.w;
            pp += __shfl_xor(pp, 32, 64);
            pp += __shfl_xor(pp, 16, 64);
            pp += __shfl_xor(pp, 8, 64);
            pp += __shfl_xor(pp, 4, 64);
            pp += __shfl_xor(pp, 2, 64);
            pp += __shfl_xor(pp, 1, 64);
            if (lane == 0) lds_pp[par][wid] = pp;
        }
    }

    // ---- epilogue: out[T-1] from the last iteration's pred partials ----
    __syncthreads();
    if (wid == 0 && lane < 16) {
        float pv = lds_pp[T_STEPS & 1][lane];
        pv += __shfl_xor(pv, 8, 64);
        pv += __shfl_xor(pv, 4, 64);
        pv += __shfl_xor(pv, 2, 64);
        pv += __shfl_xor(pv, 1, 64);
        if (lane == 0) out[(size_t)(T_STEPS - 1) * OUTPUT_N + bid] = pv;
    }
}

extern "C" void kernel_launch(void* const* d_in, const int* in_sizes, int n_in,
                              void* d_out, int out_size, void* d_ws, size_t ws_size,
                              hipStream_t stream) {
    const float* X      = (const float*)d_in[0];
    const float* state0 = (const float*)d_in[1];
    const float* W_in   = (const float*)d_in[2];
    const float* W_res  = (const float*)d_in[3];
    const float* W_out  = (const float*)d_in[4];
    float* out = (float*)d_out;

    float* stbuf = (float*)d_ws;                                     // 32 KiB
    int*   flags = (int*)((char*)d_ws + 2 * RES_N * sizeof(float));  // 2 KiB

    // Flags must start at 0 every call (ws is NOT re-poisoned between replays).
    (void)hipMemsetAsync(flags, 0, 2 * NB * sizeof(int), stream);

    esn_persistent<<<dim3(NB), dim3(NT), 0, stream>>>(
        X, state0, W_in, W_res, W_out, out, stbuf, flags);
}